// Round 1
// baseline (3180.369 us; speedup 1.0000x reference)
//
#include <hip/hip_runtime.h>
#include <hip/hip_fp16.h>

// LSTM: B=256, S=4096, D=64, H=128 (4H=512 gate cols).
// One batch element per block (256 blocks, 1/CU), 256 threads (4 waves).
// Thread t owns gate columns t and t+256:
//   t in [0,128):   (i_t, g_t)
//   t in [128,256): (f_{t-128}, o_{t-128})
// Weights for both columns live in VGPRs as packed half2 over K=192 ([Wh;Wi]).
// h (and x_t) are broadcast via v_readlane + SGPR-src v_dot2_f32_f16.

#define LSTM_B 256
#define LSTM_S 4096
#define LSTM_D 64
#define LSTM_H 128
#define LSTM_G 512

typedef unsigned int u32;

__device__ __forceinline__ u32 pack2h(float lo, float hi) {
  __half2 h = __floats2half2_rn(lo, hi);   // lo -> bits [15:0]
  return *reinterpret_cast<u32*>(&h);
}

// acc += dot(half2(a_sgpr), half2(w)), fp32 accumulate.
__device__ __forceinline__ float dot2_f16(float acc, int a_sgpr, u32 w) {
  asm("v_dot2_f32_f16 %0, %1, %2, %0" : "+v"(acc) : "s"(a_sgpr), "v"(w));
  return acc;
}

__device__ __forceinline__ float fast_sigmoid(float z) {
  // 1/(1+2^(-z*log2e)); v_exp/v_rcp handle inf/0 saturation correctly.
  return __builtin_amdgcn_rcpf(1.0f + __builtin_amdgcn_exp2f(-1.44269504f * z));
}
__device__ __forceinline__ float fast_tanh(float z) {
  // tanh(z) = 1 - 2/(1+e^{2z})
  return 1.0f - 2.0f * __builtin_amdgcn_rcpf(1.0f + __builtin_amdgcn_exp2f(2.88539008f * z));
}

__global__ __launch_bounds__(256, 1)
void lstm_fused_kernel(const float* __restrict__ x,
                       const float* __restrict__ Wi,
                       const float* __restrict__ Wh,
                       const float* __restrict__ bh,
                       const float* __restrict__ Wo,
                       const float* __restrict__ bo,
                       float* __restrict__ out) {
  const int t    = threadIdx.x;      // 0..255
  const int lane = t & 63;
  const int b    = blockIdx.x;       // batch element

  __shared__ float A0[LSTM_H];       // f exchange
  __shared__ float A1[LSTM_H];       // o exchange
  __shared__ __half Hh[LSTM_H];      // published h (fp16)
  __shared__ float R[LSTM_H];        // final reduce

  const int c0 = t;
  const int c1 = t + 256;

  // ---- load both gate columns into registers as packed half2 over K=192 ----
  u32 wA[96], wB[96];
  #pragma unroll
  for (int j = 0; j < 64; ++j) {     // rows 0..127: Wh
    wA[j] = pack2h(Wh[(2 * j) * LSTM_G + c0], Wh[(2 * j + 1) * LSTM_G + c0]);
    wB[j] = pack2h(Wh[(2 * j) * LSTM_G + c1], Wh[(2 * j + 1) * LSTM_G + c1]);
  }
  #pragma unroll
  for (int j = 0; j < 32; ++j) {     // rows 128..191: Wi
    wA[64 + j] = pack2h(Wi[(2 * j) * LSTM_G + c0], Wi[(2 * j + 1) * LSTM_G + c0]);
    wB[64 + j] = pack2h(Wi[(2 * j) * LSTM_G + c1], Wi[(2 * j + 1) * LSTM_G + c1]);
  }
  const float bh0 = bh[c0];
  const float bh1 = bh[c1];

  const float* xb = x + (size_t)b * (LSTM_S * LSTM_D);
  const int xl = lane & 31;          // lanes 32..63 mirror 0..31 (harmless)

  // step-0 x pair
  float2 xv = *reinterpret_cast<const float2*>(xb + 2 * xl);
  u32 xpair = pack2h(xv.x, xv.y);
  u32 hpair = 0u;                    // h0 = 0 (fp16 zeros)
  float c = 0.0f, hval = 0.0f;

  for (int s = 0; s < LSTM_S; ++s) {
    // prefetch next step's x pair (hidden under the dot chain)
    const int sn = (s + 1 < LSTM_S) ? s + 1 : s;
    float2 xnv = *reinterpret_cast<const float2*>(xb + (size_t)sn * LSTM_D + 2 * xl);

    float acc0 = bh0, acc1 = bh1;
    #pragma unroll
    for (int j = 0; j < 64; ++j) {   // h contribution (K rows 0..127)
      int hp = __builtin_amdgcn_readlane((int)hpair, j);
      acc0 = dot2_f16(acc0, hp, wA[j]);
      acc1 = dot2_f16(acc1, hp, wB[j]);
    }
    #pragma unroll
    for (int j = 0; j < 32; ++j) {   // x contribution (K rows 128..191)
      int xp = __builtin_amdgcn_readlane((int)xpair, j);
      acc0 = dot2_f16(acc0, xp, wA[64 + j]);
      acc1 = dot2_f16(acc1, xp, wB[64 + j]);
    }

    // activations: a0 = sigmoid (i or f); a1 = tanh (g) for t<128 else sigmoid (o)
    float a0 = fast_sigmoid(acc0);
    float a1 = (t < LSTM_H) ? fast_tanh(acc1) : fast_sigmoid(acc1);

    if (t >= LSTM_H) { A0[t - LSTM_H] = a0; A1[t - LSTM_H] = a1; }
    __syncthreads();
    if (t < LSTM_H) {
      const float f = A0[t];
      const float o = A1[t];
      c = f * c + a0 * a1;           // c = f*c + i*g
      hval = o * fast_tanh(c);
      Hh[t] = __float2half(hval);
    }
    __syncthreads();

    hpair = *reinterpret_cast<const u32*>(&Hh[2 * lane]);  // (h[2l], h[2l+1])
    xpair = pack2h(xnv.x, xnv.y);
  }

  // ---- output: out[b] = h_last @ Wo + bo ----
  if (t < LSTM_H) R[t] = hval * Wo[t];
  __syncthreads();
  if (t < 64) {
    float v = R[t] + R[t + 64];
    #pragma unroll
    for (int off = 32; off; off >>= 1) v += __shfl_down(v, off);
    if (t == 0) out[b] = v + bo[0];
  }
}

extern "C" void kernel_launch(void* const* d_in, const int* in_sizes, int n_in,
                              void* d_out, int out_size, void* d_ws, size_t ws_size,
                              hipStream_t stream) {
  const float* x  = (const float*)d_in[0];
  const float* Wi = (const float*)d_in[1];
  const float* Wh = (const float*)d_in[2];
  const float* bh = (const float*)d_in[3];
  const float* Wo = (const float*)d_in[4];
  const float* bo = (const float*)d_in[5];
  float* out = (float*)d_out;

  lstm_fused_kernel<<<LSTM_B, 256, 0, stream>>>(x, Wi, Wh, bh, Wo, bo, out);
}

// Round 3
// 3170.932 us; speedup vs baseline: 1.0030x; 1.0030x over previous
//
#include <hip/hip_runtime.h>
#include <hip/hip_fp16.h>

// LSTM: B=256, S=4096, D=64, H=128 (4H=512 gate cols, layout [i|f|g|o]).
// One batch element per block (256 blocks = 1/CU), 256 threads (4 waves, 1/SIMD).
// Unit u = 32*wave + (t&31). Lane l (bit5=0) owns (i_u, g_u); lane l^32 owns
// (f_u, o_u) -> partner exchange is an in-wave __shfl_xor(32), no barrier.
// Weights packed half2 in VGPRs (chunk-staged, sched-fenced, to avoid AGPR
// demotion). h broadcast via double-buffered LDS + one barrier per step.
// Arithmetic is bit-identical to the round-1 kernel (passed at 4.88e-4).

#define LSTM_B 256
#define LSTM_S 4096
#define LSTM_D 64
#define LSTM_H 128
#define LSTM_G 512

typedef unsigned int u32;

__device__ __forceinline__ u32 pack2h(float lo, float hi) {
  __half2 h = __floats2half2_rn(lo, hi);   // lo -> bits [15:0]
  return *reinterpret_cast<u32*>(&h);
}

// acc += dot(half2(a_sgpr), half2(w)), fp32 accumulate.
__device__ __forceinline__ float dot2_f16(float acc, int a_sgpr, u32 w) {
  asm("v_dot2_f32_f16 %0, %1, %2, %0" : "+v"(acc) : "s"(a_sgpr), "v"(w));
  return acc;
}

__device__ __forceinline__ float fast_sigmoid(float z) {
  return __builtin_amdgcn_rcpf(1.0f + __builtin_amdgcn_exp2f(-1.44269504f * z));
}

__global__ __launch_bounds__(256, 1)
void lstm_fused_kernel(const float* __restrict__ x,
                       const float* __restrict__ Wi,
                       const float* __restrict__ Wh,
                       const float* __restrict__ bh,
                       const float* __restrict__ Wo,
                       const float* __restrict__ bo,
                       float* __restrict__ out) {
  const int t    = threadIdx.x;        // 0..255
  const int lane = t & 63;
  const int b    = blockIdx.x;
  const int wv   = t >> 6;             // wave 0..3
  const bool hi  = (t >> 5) & 1;       // bit5: (i,g)-half vs (f,o)-half
  const int u    = 32 * wv + (t & 31); // unit id 0..127

  __shared__ __half Hh[2][LSTM_H];     // double-buffered published h (fp16)
  __shared__ float R[LSTM_H];          // final reduce

  // gate columns in [i|f|g|o] layout
  const int c0 = u + (hi ? 128 : 0);         // i_u or f_u
  const int c1 = u + 256 + (hi ? 128 : 0);   // g_u or o_u

  // ---- stage both gate columns into VGPRs as packed half2 over K=192 ----
  // Chunked with scheduling fences: caps live load-temps so the 192 packed
  // values can be allocated as arch VGPRs (not demoted to AGPRs).
  u32 wA[96], wB[96];
  #pragma unroll
  for (int ch = 0; ch < 8; ++ch) {     // Wh: 64 row-pairs
    #pragma unroll
    for (int uu = 0; uu < 8; ++uu) {
      const int j = ch * 8 + uu;
      wA[j] = pack2h(Wh[(2 * j) * LSTM_G + c0], Wh[(2 * j + 1) * LSTM_G + c0]);
      wB[j] = pack2h(Wh[(2 * j) * LSTM_G + c1], Wh[(2 * j + 1) * LSTM_G + c1]);
    }
    __builtin_amdgcn_sched_barrier(0);
  }
  #pragma unroll
  for (int ch = 0; ch < 4; ++ch) {     // Wi: 32 row-pairs
    #pragma unroll
    for (int uu = 0; uu < 8; ++uu) {
      const int k = ch * 8 + uu;
      wA[64 + k] = pack2h(Wi[(2 * k) * LSTM_G + c0], Wi[(2 * k + 1) * LSTM_G + c0]);
      wB[64 + k] = pack2h(Wi[(2 * k) * LSTM_G + c1], Wi[(2 * k + 1) * LSTM_G + c1]);
    }
    __builtin_amdgcn_sched_barrier(0);
  }

  const float bh0 = bh[c0];
  const float bh1 = bh[c1];
  // g1 activation blend (bit-identical to branch version under fma contract):
  //   hi==0 (g gate, tanh):    r=rcp(1+exp2( 2.885*z)); g1 = 1 + (-2)*r
  //   hi==1 (o gate, sigmoid): r=rcp(1+exp2(-1.443*z)); g1 = 0 + ( 1)*r
  const float kG = hi ? -1.44269504f : 2.88539008f;
  const float AG = hi ? 0.0f : 1.0f;
  const float BG = hi ? 1.0f : -2.0f;

  const float* xb = x + (size_t)b * (LSTM_S * LSTM_D);
  const int xl = lane & 31;            // lanes 32..63 mirror 0..31 (harmless)

  float2 xv0 = *reinterpret_cast<const float2*>(xb + 2 * xl);   // x(0)
  u32 xpair = pack2h(xv0.x, xv0.y);
  u32 hpair = 0u;                      // h0 = 0
  float c = 0.0f, hval = 0.0f;
  __builtin_amdgcn_sched_barrier(0);
  __syncthreads();

  for (int s = 0; s < LSTM_S; ++s) {
    // prefetch next step's x pair (latency hidden under the dot chain)
    const int sn = (s + 1 < LSTM_S) ? s + 1 : s;
    float2 xnv = *reinterpret_cast<const float2*>(xb + (size_t)sn * LSTM_D + 2 * xl);

    // z chain: bh -> 64 h-dots (lane order) -> 32 x-dots. Same as round 1.
    float acc0 = bh0, acc1 = bh1;
    #pragma unroll
    for (int j = 0; j < 64; ++j) {
      int hp = __builtin_amdgcn_readlane((int)hpair, j);
      acc0 = dot2_f16(acc0, hp, wA[j]);
      acc1 = dot2_f16(acc1, hp, wB[j]);
    }
    #pragma unroll
    for (int j = 0; j < 32; ++j) {
      int xp = __builtin_amdgcn_readlane((int)xpair, j);
      acc0 = dot2_f16(acc0, xp, wA[64 + j]);
      acc1 = dot2_f16(acc1, xp, wB[64 + j]);
    }

    const float g0 = fast_sigmoid(acc0);   // i (hi==0) or f (hi==1)
    const float r1 = __builtin_amdgcn_rcpf(1.0f + __builtin_amdgcn_exp2f(kG * acc1));
    const float g1 = AG + BG * r1;         // tanh(g) or sigmoid(o)

    // in-wave partner exchange: lane l <-> lane l^32 (same unit u)
    const float pg0 = __shfl_xor(g0, 32);
    const float pg1 = __shfl_xor(g1, 32);
    const float iv = hi ? pg0 : g0;
    const float gv = hi ? pg1 : g1;
    const float fv = hi ? g0 : pg0;
    const float ov = hi ? g1 : pg1;

    // c/h update (computed redundantly on both partners; identical values)
    c = fv * c + iv * gv;
    hval = ov * (1.0f - 2.0f * __builtin_amdgcn_rcpf(
                     1.0f + __builtin_amdgcn_exp2f(2.88539008f * c)));
    if (!hi) Hh[(s + 1) & 1][u] = __float2half(hval);

    __syncthreads();                       // single barrier per step
    hpair = *reinterpret_cast<const u32*>(
        reinterpret_cast<const char*>(Hh[(s + 1) & 1]) + 4 * lane);
    xpair = pack2h(xnv.x, xnv.y);
  }

  // ---- output: out[b] = h_last @ Wo + bo ----
  if (!hi) R[u] = hval * Wo[u];
  __syncthreads();
  if (t < 64) {
    float v = R[t] + R[t + 64];
    #pragma unroll
    for (int off = 32; off; off >>= 1) v += __shfl_down(v, off);
    if (t == 0) out[b] = v + bo[0];
  }
}

extern "C" void kernel_launch(void* const* d_in, const int* in_sizes, int n_in,
                              void* d_out, int out_size, void* d_ws, size_t ws_size,
                              hipStream_t stream) {
  const float* x  = (const float*)d_in[0];
  const float* Wi = (const float*)d_in[1];
  const float* Wh = (const float*)d_in[2];
  const float* bh = (const float*)d_in[3];
  const float* Wo = (const float*)d_in[4];
  const float* bo = (const float*)d_in[5];
  float* out = (float*)d_out;

  lstm_fused_kernel<<<LSTM_B, 256, 0, stream>>>(x, Wi, Wh, bh, Wo, bo, out);
}

// Round 6
// 3164.455 us; speedup vs baseline: 1.0050x; 1.0020x over previous
//
#include <hip/hip_runtime.h>
#include <hip/hip_fp16.h>

// LSTM: B=256, S=4096, D=64, H=128 (4H=512 gate cols, layout [i|f|g|o]).
// One batch element per block (256 blocks = 1/CU), 256 threads (4 waves).
// This is the round-3 PASSING kernel (absmax 4.882812e-04) with exactly one
// change: __launch_bounds__(256,1) -> (256,2). Budget 256 regs >= demand
// (~220), so the allocator can keep the 192 packed-weight regs in arch VGPRs
// instead of AGPR-home + v_accvgpr_read copies (R3: VGPR_Count=112, ~330
// excess VALU instrs/step). No semantic change; output must be bit-identical.

#define LSTM_B 256
#define LSTM_S 4096
#define LSTM_D 64
#define LSTM_H 128
#define LSTM_G 512

typedef unsigned int u32;

__device__ __forceinline__ u32 pack2h(float lo, float hi) {
  __half2 h = __floats2half2_rn(lo, hi);   // lo -> bits [15:0]
  return *reinterpret_cast<u32*>(&h);
}

// acc += dot(half2(a_sgpr), half2(w)), fp32 accumulate.
__device__ __forceinline__ float dot2_f16(float acc, int a_sgpr, u32 w) {
  asm("v_dot2_f32_f16 %0, %1, %2, %0" : "+v"(acc) : "s"(a_sgpr), "v"(w));
  return acc;
}

__device__ __forceinline__ float fast_sigmoid(float z) {
  return __builtin_amdgcn_rcpf(1.0f + __builtin_amdgcn_exp2f(-1.44269504f * z));
}

__global__ __launch_bounds__(256, 2)
void lstm_fused_kernel(const float* __restrict__ x,
                       const float* __restrict__ Wi,
                       const float* __restrict__ Wh,
                       const float* __restrict__ bh,
                       const float* __restrict__ Wo,
                       const float* __restrict__ bo,
                       float* __restrict__ out) {
  const int t    = threadIdx.x;        // 0..255
  const int lane = t & 63;
  const int b    = blockIdx.x;
  const int wv   = t >> 6;             // wave 0..3
  const bool hi  = (t >> 5) & 1;       // bit5: (i,g)-half vs (f,o)-half
  const int u    = 32 * wv + (t & 31); // unit id 0..127

  __shared__ __half Hh[2][LSTM_H];     // double-buffered published h (fp16)
  __shared__ float R[LSTM_H];          // final reduce

  // gate columns in [i|f|g|o] layout
  const int c0 = u + (hi ? 128 : 0);         // i_u or f_u
  const int c1 = u + 256 + (hi ? 128 : 0);   // g_u or o_u

  // ---- stage both gate columns into VGPRs as packed half2 over K=192 ----
  u32 wA[96], wB[96];
  #pragma unroll
  for (int ch = 0; ch < 8; ++ch) {     // Wh: 64 row-pairs
    #pragma unroll
    for (int uu = 0; uu < 8; ++uu) {
      const int j = ch * 8 + uu;
      wA[j] = pack2h(Wh[(2 * j) * LSTM_G + c0], Wh[(2 * j + 1) * LSTM_G + c0]);
      wB[j] = pack2h(Wh[(2 * j) * LSTM_G + c1], Wh[(2 * j + 1) * LSTM_G + c1]);
    }
    __builtin_amdgcn_sched_barrier(0);
  }
  #pragma unroll
  for (int ch = 0; ch < 4; ++ch) {     // Wi: 32 row-pairs
    #pragma unroll
    for (int uu = 0; uu < 8; ++uu) {
      const int k = ch * 8 + uu;
      wA[64 + k] = pack2h(Wi[(2 * k) * LSTM_G + c0], Wi[(2 * k + 1) * LSTM_G + c0]);
      wB[64 + k] = pack2h(Wi[(2 * k) * LSTM_G + c1], Wi[(2 * k + 1) * LSTM_G + c1]);
    }
    __builtin_amdgcn_sched_barrier(0);
  }

  const float bh0 = bh[c0];
  const float bh1 = bh[c1];
  // g1 activation blend (bit-identical to branch version under fma contract):
  //   hi==0 (g gate, tanh):    r=rcp(1+exp2( 2.885*z)); g1 = 1 + (-2)*r
  //   hi==1 (o gate, sigmoid): r=rcp(1+exp2(-1.443*z)); g1 = 0 + ( 1)*r
  const float kG = hi ? -1.44269504f : 2.88539008f;
  const float AG = hi ? 0.0f : 1.0f;
  const float BG = hi ? 1.0f : -2.0f;

  const float* xb = x + (size_t)b * (LSTM_S * LSTM_D);
  const int xl = lane & 31;            // lanes 32..63 mirror 0..31 (harmless)

  float2 xv0 = *reinterpret_cast<const float2*>(xb + 2 * xl);   // x(0)
  u32 xpair = pack2h(xv0.x, xv0.y);
  u32 hpair = 0u;                      // h0 = 0
  float c = 0.0f, hval = 0.0f;
  __builtin_amdgcn_sched_barrier(0);
  __syncthreads();

  for (int s = 0; s < LSTM_S; ++s) {
    // prefetch next step's x pair (latency hidden under the dot chain)
    const int sn = (s + 1 < LSTM_S) ? s + 1 : s;
    float2 xnv = *reinterpret_cast<const float2*>(xb + (size_t)sn * LSTM_D + 2 * xl);

    // z chain: bh -> 64 h-dots (asc) -> 32 x-dots (asc). Order as round 1.
    float acc0 = bh0, acc1 = bh1;
    #pragma unroll
    for (int j = 0; j < 64; ++j) {
      int hp = __builtin_amdgcn_readlane((int)hpair, j);
      acc0 = dot2_f16(acc0, hp, wA[j]);
      acc1 = dot2_f16(acc1, hp, wB[j]);
    }
    #pragma unroll
    for (int j = 0; j < 32; ++j) {
      int xp = __builtin_amdgcn_readlane((int)xpair, j);
      acc0 = dot2_f16(acc0, xp, wA[64 + j]);
      acc1 = dot2_f16(acc1, xp, wB[64 + j]);
    }

    const float g0 = fast_sigmoid(acc0);   // i (hi==0) or f (hi==1)
    const float r1 = __builtin_amdgcn_rcpf(1.0f + __builtin_amdgcn_exp2f(kG * acc1));
    const float g1 = AG + BG * r1;         // tanh(g) or sigmoid(o)

    // in-wave partner exchange: lane l <-> lane l^32 (same unit u)
    const float pg0 = __shfl_xor(g0, 32);
    const float pg1 = __shfl_xor(g1, 32);
    const float iv = hi ? pg0 : g0;
    const float gv = hi ? pg1 : g1;
    const float fv = hi ? g0 : pg0;
    const float ov = hi ? g1 : pg1;

    // c/h update (computed redundantly on both partners; identical values)
    c = fv * c + iv * gv;
    hval = ov * (1.0f - 2.0f * __builtin_amdgcn_rcpf(
                     1.0f + __builtin_amdgcn_exp2f(2.88539008f * c)));
    if (!hi) Hh[(s + 1) & 1][u] = __float2half(hval);

    __syncthreads();                       // single barrier per step
    hpair = *reinterpret_cast<const u32*>(
        reinterpret_cast<const char*>(Hh[(s + 1) & 1]) + 4 * lane);
    xpair = pack2h(xnv.x, xnv.y);
  }

  // ---- output: out[b] = h_last @ Wo + bo ----
  if (!hi) R[u] = hval * Wo[u];
  __syncthreads();
  if (t < 64) {
    float v = R[t] + R[t + 64];
    #pragma unroll
    for (int off = 32; off; off >>= 1) v += __shfl_down(v, off);
    if (t == 0) out[b] = v + bo[0];
  }
}

extern "C" void kernel_launch(void* const* d_in, const int* in_sizes, int n_in,
                              void* d_out, int out_size, void* d_ws, size_t ws_size,
                              hipStream_t stream) {
  const float* x  = (const float*)d_in[0];
  const float* Wi = (const float*)d_in[1];
  const float* Wh = (const float*)d_in[2];
  const float* bh = (const float*)d_in[3];
  const float* Wo = (const float*)d_in[4];
  const float* bo = (const float*)d_in[5];
  float* out = (float*)d_out;

  lstm_fused_kernel<<<LSTM_B, 256, 0, stream>>>(x, Wi, Wh, bh, Wo, bo, out);
}